// Round 7
// baseline (127.014 us; speedup 1.0000x reference)
//
#include <hip/hip_runtime.h>
#include <hip/hip_bf16.h>

typedef __attribute__((ext_vector_type(8))) short short8;   // 8 x bf16 (4 VGPRs)
typedef __attribute__((ext_vector_type(4))) float f32x4;
using bf16 = __hip_bfloat16;

// Problem sizes: B=32, LQ=LKV=256, HID=1024, EMB=1024, K_fc=2048

__device__ __forceinline__ void glds16(const void* g, void* lds) {
  __builtin_amdgcn_global_load_lds(
      (const __attribute__((address_space(1))) void*)g,
      (__attribute__((address_space(3))) void*)lds, 16, 0, 0);
}

// ---------------- K1: gathers + f32->bf16 conversions (merged) ----------------
__global__ __launch_bounds__(256) void k1_prep(
    const int* __restrict__ captions, const float* __restrict__ Wa,
    const float* __restrict__ H, const float* __restrict__ fcw,
    const int* __restrict__ targets, const float* __restrict__ Wc,
    bf16* __restrict__ EA, bf16* __restrict__ X, bf16* __restrict__ FW,
    bf16* __restrict__ ECT) {
  __shared__ float T[64][67];
  int task = blockIdx.x;
  int tid = threadIdx.x;
  if (task < 17408) {
    const float* src;
    bf16* dst;
    int n;
    if (task < 8192) {
      src = Wa + (size_t)captions[task] * 1024;
      dst = EA + (size_t)task * 1024;
      n = 1024;
    } else if (task < 16384) {
      int t = task - 8192;
      src = H + (size_t)t * 1024;
      dst = X + (size_t)t * 2048;
      n = 1024;
    } else {
      int t = task - 16384;
      src = fcw + (size_t)t * 2048;
      dst = FW + (size_t)t * 2048;
      n = 2048;
    }
    for (int c = tid * 4; c < n; c += 1024) {
      float4 v = *(const float4*)(src + c);
      __hip_bfloat162 p0, p1;
      p0.x = __float2bfloat16(v.x); p0.y = __float2bfloat16(v.y);
      p1.x = __float2bfloat16(v.z); p1.y = __float2bfloat16(v.w);
      *(__hip_bfloat162*)(dst + c) = p0;
      *(__hip_bfloat162*)(dst + c + 2) = p1;
    }
    return;
  }
  int bid = task - 17408;
  int b = bid >> 6;
  int kt = (bid >> 4) & 3;
  int ht = bid & 15;
#pragma unroll
  for (int p = 0; p < 4; ++p) {
    int k = p * 16 + (tid >> 4);
    int idx = targets[b * 256 + kt * 64 + k];
    const float* s = Wc + (size_t)idx * 1024 + ht * 64 + (tid & 15) * 4;
    float4 v = *(const float4*)s;
    int c = (tid & 15) * 4;
    T[k][c] = v.x; T[k][c + 1] = v.y; T[k][c + 2] = v.z; T[k][c + 3] = v.w;
  }
  __syncthreads();
#pragma unroll
  for (int p = 0; p < 8; ++p) {
    int h = p * 8 + (tid >> 5);
    int k = (tid & 31) * 2;
    __hip_bfloat162 o;
    o.x = __float2bfloat16(T[k][h]);
    o.y = __float2bfloat16(T[k + 1][h]);
    *(__hip_bfloat162*)(ECT + ((size_t)b * 1024 + ht * 64 + h) * 256 + kt * 64 + k) = o;
  }
}

// ---------------- K23: fused scores + masked-exp softmax + PV ----------------
__global__ __launch_bounds__(256, 1) void k23_scores_pv(
    bf16* __restrict__ X, const bf16* __restrict__ EA,
    const bf16* __restrict__ ECT, const float* __restrict__ mask) {
  __shared__ __align__(16) char smem[16 * 1024 + 512 + 128 * 1024];
  bf16* p_lds = (bf16*)smem;                    // [32][256] swizzled
  float* red  = (float*)(smem + 16 * 1024);     // [4][32]
  bf16* big   = (bf16*)(smem + 16 * 1024 + 512);// 128KB: scores As+Bs / PV B2

  int p = blockIdx.x;
  int wg = (p & 7) * 32 + (p >> 3);   // chunked XCD swizzle (256 % 8 == 0)
  int b = wg >> 3;
  int mb = wg & 7;
  int tid = threadIdx.x, w = tid >> 6, l = tid & 63;

  const bf16* Ag = X + ((size_t)b * 256 + mb * 32) * 2048;
  const bf16* Bg = EA + (size_t)b * 256 * 1024;
  bf16* As = big;              // 32 x 64
  bf16* Bs = big + 32 * 64;    // 256 x 64

  f32x4 sacc[2][4];
  f32x4 zero = {0.f, 0.f, 0.f, 0.f};
#pragma unroll
  for (int m2 = 0; m2 < 2; ++m2)
#pragma unroll
    for (int n = 0; n < 4; ++n) sacc[m2][n] = zero;

  for (int kt = 0; kt < 16; ++kt) {
    {
      int row = tid >> 3, ss = (tid & 7) ^ (row & 7);
      glds16(Ag + (size_t)row * 2048 + kt * 64 + ss * 8,
             As + (size_t)w * 64 * 8);
    }
#pragma unroll
    for (int i = 0; i < 8; ++i) {
      int c = i * 256 + tid;
      int row = c >> 3, ss = (c & 7) ^ (row & 7);
      glds16(Bg + (size_t)row * 1024 + kt * 64 + ss * 8,
             Bs + (size_t)(i * 256 + w * 64) * 8);
    }
    __syncthreads();
#pragma unroll
    for (int kk = 0; kk < 2; ++kk) {
      short8 a2[2];
#pragma unroll
      for (int m2 = 0; m2 < 2; ++m2) {
        int ar = m2 * 16 + (l & 15);
        int sl = kk * 4 + (l >> 4);
        a2[m2] = *(const short8*)(As + ar * 64 + ((sl ^ (ar & 7)) * 8));
      }
#pragma unroll
      for (int n = 0; n < 4; ++n) {
        int rb = w * 64 + n * 16 + (l & 15);
        int sl = kk * 4 + (l >> 4);
        short8 bfr = *(const short8*)(Bs + rb * 64 + ((sl ^ (rb & 7)) * 8));
#pragma unroll
        for (int m2 = 0; m2 < 2; ++m2)
          sacc[m2][n] = __builtin_amdgcn_mfma_f32_16x16x32_bf16(
              a2[m2], bfr, sacc[m2][n], 0, 0, 0);
      }
    }
    __syncthreads();
  }

  const float* mrow = mask + ((size_t)b * 256 + mb * 32) * 256;
  float s[2][4] = {{0.f, 0.f, 0.f, 0.f}, {0.f, 0.f, 0.f, 0.f}};
#pragma unroll
  for (int m2 = 0; m2 < 2; ++m2)
#pragma unroll
    for (int n = 0; n < 4; ++n)
#pragma unroll
      for (int i = 0; i < 4; ++i) {
        int r = m2 * 16 + ((l >> 4) << 2) + i;
        int c = w * 64 + n * 16 + (l & 15);
        float mv = mrow[r * 256 + c];
        mv = fminf(fmaxf(mv, 0.f), 1.f);
        float ev = expf(sacc[m2][n][i]) * mv;
        sacc[m2][n][i] = ev;
        s[m2][i] += ev;
      }
#pragma unroll
  for (int msk = 1; msk < 16; msk <<= 1)
#pragma unroll
    for (int m2 = 0; m2 < 2; ++m2)
#pragma unroll
      for (int i = 0; i < 4; ++i) s[m2][i] += __shfl_xor(s[m2][i], msk, 64);
  if ((l & 15) == 0) {
#pragma unroll
    for (int m2 = 0; m2 < 2; ++m2)
#pragma unroll
      for (int i = 0; i < 4; ++i)
        red[w * 32 + m2 * 16 + ((l >> 4) << 2) + i] = s[m2][i];
  }
  __syncthreads();
  float inv[2][4];
#pragma unroll
  for (int m2 = 0; m2 < 2; ++m2)
#pragma unroll
    for (int i = 0; i < 4; ++i) {
      int r = m2 * 16 + ((l >> 4) << 2) + i;
      float tot = red[r] + red[32 + r] + red[64 + r] + red[96 + r];
      inv[m2][i] = 1.f / (tot + 1e-10f);
    }
#pragma unroll
  for (int m2 = 0; m2 < 2; ++m2)
#pragma unroll
    for (int n = 0; n < 4; ++n)
#pragma unroll
      for (int i = 0; i < 4; ++i) {
        int r = m2 * 16 + ((l >> 4) << 2) + i;
        int c = w * 64 + n * 16 + (l & 15);
        float pv = sacc[m2][n][i] * inv[m2][i];
        p_lds[r * 256 + (((c >> 3) ^ (r & 7)) << 3) + (c & 7)] =
            __float2bfloat16(pv);
      }
  __syncthreads();

  bf16* XO = X + ((size_t)b * 256 + mb * 32) * 2048 + 1024;
  for (int np = 0; np < 2; ++np) {
    f32x4 acc[2][8];
#pragma unroll
    for (int m2 = 0; m2 < 2; ++m2)
#pragma unroll
      for (int n = 0; n < 8; ++n) acc[m2][n] = zero;

#pragma unroll
    for (int it = 0; it < 16; ++it) {
      int g = it * 64 + l;
      int row = g >> 3, ss = (g & 7) ^ (row & 7);
      glds16(ECT + ((size_t)b * 1024 + np * 512 + w * 128 + row) * 256 + ss * 8,
             big + (size_t)(0 * 4 + w) * 8192 + (size_t)it * 512);
    }
    __syncthreads();
    for (int kt = 0; kt < 4; ++kt) {
      int cur = kt & 1;
      if (kt < 3) {
#pragma unroll
        for (int it = 0; it < 16; ++it) {
          int g = it * 64 + l;
          int row = g >> 3, ss = (g & 7) ^ (row & 7);
          glds16(ECT + ((size_t)b * 1024 + np * 512 + w * 128 + row) * 256 +
                     (kt + 1) * 64 + ss * 8,
                 big + (size_t)((cur ^ 1) * 4 + w) * 8192 + (size_t)it * 512);
        }
      }
      const bf16* Bw = big + (size_t)(cur * 4 + w) * 8192;
#pragma unroll
      for (int kk = 0; kk < 2; ++kk) {
        short8 a2[2];
#pragma unroll
        for (int m2 = 0; m2 < 2; ++m2) {
          int ar = m2 * 16 + (l & 15);
          int sl = kt * 8 + kk * 4 + (l >> 4);
          a2[m2] = *(const short8*)(p_lds + ar * 256 + ((sl ^ (ar & 7)) * 8));
        }
#pragma unroll
        for (int n = 0; n < 8; ++n) {
          int rb = n * 16 + (l & 15);
          int sl = kk * 4 + (l >> 4);
          short8 bfr = *(const short8*)(Bw + rb * 64 + ((sl ^ (rb & 7)) * 8));
#pragma unroll
          for (int m2 = 0; m2 < 2; ++m2)
            acc[m2][n] = __builtin_amdgcn_mfma_f32_16x16x32_bf16(
                a2[m2], bfr, acc[m2][n], 0, 0, 0);
        }
      }
      __syncthreads();
    }
#pragma unroll
    for (int m2 = 0; m2 < 2; ++m2)
#pragma unroll
      for (int n = 0; n < 8; ++n) {
        int rl = m2 * 16 + ((l >> 4) << 2);
        int col = np * 512 + w * 128 + n * 16 + (l & 15);
#pragma unroll
        for (int i = 0; i < 4; ++i)
          XO[(size_t)(rl + i) * 2048 + col] = __float2bfloat16(acc[m2][n][i]);
      }
  }
}

// ---------------- K4: out = normalize(X @ FW^T + fc_b + 1e-10) ----------------
// Same proven sync-only 2-phase dbuf loop as R5/R6. NEW: fused row-L2-norm
// epilogue via hand-rolled grid barrier. Grid 256 x 96KB LDS = hard 1 block/CU
// -> all blocks co-resident -> spin cannot deadlock. Partials are plain-stored
// (every entry rewritten each call), made visible by __threadfence (L2
// writeback) + release atomicAdd; readers acquire-spin then agent-scope
// atomic loads (bypass stale L1/L2 across XCDs).
#define K4A (256 * 64)
#define K4B (128 * 64)

__device__ __forceinline__ void k4_stage(const bf16* __restrict__ Ag,
                                         const bf16* __restrict__ Bg, int kt,
                                         bf16* As, bf16* Bs, int tid, int w) {
#pragma unroll
  for (int i = 0; i < 4; ++i) {
    int c = i * 512 + tid;
    int row = c >> 3, ss = (c & 7) ^ (row & 7);
    glds16(Ag + (size_t)row * 2048 + kt * 64 + ss * 8,
           As + (size_t)(i * 512 + w * 64) * 8);
  }
#pragma unroll
  for (int i = 0; i < 2; ++i) {
    int c = i * 512 + tid;
    int row = c >> 3, ss = (c & 7) ^ (row & 7);
    glds16(Bg + (size_t)row * 2048 + kt * 64 + ss * 8,
           Bs + (size_t)(i * 512 + w * 64) * 8);
  }
}

__device__ __forceinline__ void k4_tile(const bf16* As, const bf16* Bs,
                                        int wr, int wc, int l,
                                        f32x4 (&acc)[4][4]) {
  short8 a[2][4], b[2][4];
#pragma unroll
  for (int kk = 0; kk < 2; ++kk)
#pragma unroll
    for (int n = 0; n < 4; ++n) {
      int row = wc * 64 + n * 16 + (l & 15);
      int slot = kk * 4 + (l >> 4);
      b[kk][n] = *(const short8*)(Bs + row * 64 + ((slot ^ (row & 7)) * 8));
    }
#pragma unroll
  for (int kk = 0; kk < 2; ++kk)
#pragma unroll
    for (int m = 0; m < 4; ++m) {
      int row = wr * 64 + m * 16 + (l & 15);
      int slot = kk * 4 + (l >> 4);
      a[kk][m] = *(const short8*)(As + row * 64 + ((slot ^ (row & 7)) * 8));
    }
  __builtin_amdgcn_s_setprio(1);
#pragma unroll
  for (int kk = 0; kk < 2; ++kk)
#pragma unroll
    for (int m = 0; m < 4; ++m)
#pragma unroll
      for (int n = 0; n < 4; ++n)
        acc[m][n] = __builtin_amdgcn_mfma_f32_16x16x32_bf16(
            a[kk][m], b[kk][n], acc[m][n], 0, 0, 0);
  __builtin_amdgcn_s_setprio(0);
}

__global__ __launch_bounds__(512, 1) void k4_fc_norm(
    const bf16* __restrict__ X, const bf16* __restrict__ FW,
    const float* __restrict__ fcb, float* __restrict__ out,
    float* __restrict__ ssqp, unsigned* __restrict__ cnt) {
  __shared__ __align__(16) bf16 As[2][K4A];   // 64 KB
  __shared__ __align__(16) bf16 Bs[2][K4B];   // 32 KB
  int p = blockIdx.x;
  int wg = (p & 7) * 32 + (p >> 3);   // chunked XCD swizzle (256 % 8 == 0)
  int mb = wg >> 3;   // 0..31
  int nb = wg & 7;    // 0..7
  int tid = threadIdx.x, w = tid >> 6, l = tid & 63;
  int wr = w >> 1, wc = w & 1;
  f32x4 acc[4][4];
  f32x4 zero = {0.f, 0.f, 0.f, 0.f};
#pragma unroll
  for (int m = 0; m < 4; ++m)
#pragma unroll
    for (int n = 0; n < 4; ++n) acc[m][n] = zero;

  const bf16* Ag = X + (size_t)mb * 256 * 2048;
  const bf16* Bg = FW + (size_t)nb * 128 * 2048;

  k4_stage(Ag, Bg, 0, As[0], Bs[0], tid, w);
  __syncthreads();
  for (int t = 0; t < 32; ++t) {
    int cur = t & 1;
    if (t < 31)
      k4_stage(Ag, Bg, t + 1, As[cur ^ 1], Bs[cur ^ 1], tid, w);
    k4_tile(As[cur], Bs[cur], wr, wc, l, acc);
    __syncthreads();
  }

  // ---- epilogue: bias + 1e-10, per-row SSQ partials, grid barrier, norm ----
  float bias[4];
#pragma unroll
  for (int n = 0; n < 4; ++n)
    bias[n] = fcb[nb * 128 + wc * 64 + n * 16 + (l & 15)];

  float* ssq_lds = (float*)&As[0][0];   // 1 KB reuse (main loop done)
  if (tid < 256) ssq_lds[tid] = 0.f;
  __syncthreads();
#pragma unroll
  for (int m = 0; m < 4; ++m)
#pragma unroll
    for (int i = 0; i < 4; ++i) {
      float rs = 0.f;
#pragma unroll
      for (int n = 0; n < 4; ++n) {
        float v = acc[m][n][i] + bias[n] + 1e-10f;
        acc[m][n][i] = v;
        rs += v * v;
      }
      rs += __shfl_xor(rs, 1, 64);
      rs += __shfl_xor(rs, 2, 64);
      rs += __shfl_xor(rs, 4, 64);
      rs += __shfl_xor(rs, 8, 64);
      if ((l & 15) == 0)
        atomicAdd(&ssq_lds[wr * 64 + m * 16 + ((l >> 4) << 2) + i], rs);
    }
  __syncthreads();
  if (tid < 256)
    ssqp[(size_t)nb * 8192 + mb * 256 + tid] = ssq_lds[tid];
  __syncthreads();            // all partial stores issued (vmcnt drained)
  if (tid == 0) {
    __threadfence();          // write back L2 -> visible device-wide
    atomicAdd(cnt, 1u);       // device-scope by default
    while (__hip_atomic_load(cnt, __ATOMIC_ACQUIRE,
                             __HIP_MEMORY_SCOPE_AGENT) < 256u)
      __builtin_amdgcn_s_sleep(2);
  }
  __syncthreads();
  if (tid < 256) {
    int r = mb * 256 + tid;
    float ssum = 0.f;
#pragma unroll
    for (int j = 0; j < 8; ++j)
      ssum += __hip_atomic_load(&ssqp[(size_t)j * 8192 + r], __ATOMIC_RELAXED,
                                __HIP_MEMORY_SCOPE_AGENT);
    ssq_lds[tid] = 1.f / (sqrtf(ssum) + 1e-8f);
  }
  __syncthreads();
#pragma unroll
  for (int m = 0; m < 4; ++m) {
    int rl = wr * 64 + m * 16 + ((l >> 4) << 2);
    int rbase = mb * 256 + rl;
#pragma unroll
    for (int n = 0; n < 4; ++n) {
      int col = nb * 128 + wc * 64 + n * 16 + (l & 15);
#pragma unroll
      for (int i = 0; i < 4; ++i)
        out[(size_t)(rbase + i) * 1024 + col] = acc[m][n][i] * ssq_lds[rl + i];
    }
  }
}

extern "C" void kernel_launch(void* const* d_in, const int* in_sizes, int n_in,
                              void* d_out, int out_size, void* d_ws, size_t ws_size,
                              hipStream_t stream) {
  const int* captions = (const int*)d_in[0];
  const float* H = (const float*)d_in[1];
  const int* targets = (const int*)d_in[2];
  const float* mask = (const float*)d_in[3];
  const float* Wa = (const float*)d_in[4];
  const float* Wc = (const float*)d_in[5];
  const float* fcw = (const float*)d_in[6];
  const float* fcb = (const float*)d_in[7];
  float* out = (float*)d_out;

  char* ws = (char*)d_ws;
  bf16* EA = (bf16*)(ws);                        // 16 MB [32][256][1024]
  bf16* ECT = (bf16*)(ws + (16u << 20));         // 16 MB [32][1024][256]
  float* ssqp = (float*)(ws + (32u << 20));      // 256 KB [8][8192]
  unsigned* cnt = (unsigned*)(ws + (33u << 20)); // 4 B
  bf16* X = (bf16*)(ws + (36u << 20));           // 32 MB [8192][2048]
  bf16* FW = (bf16*)(ws + (68u << 20));          //  4 MB [1024][2048]

  hipMemsetAsync(cnt, 0, 4, stream);
  k1_prep<<<19456, 256, 0, stream>>>(captions, Wa, H, fcw, targets, Wc,
                                     EA, X, FW, ECT);
  k23_scores_pv<<<256, 256, 0, stream>>>(X, EA, ECT, mask);
  k4_fc_norm<<<256, 512, 0, stream>>>(X, FW, fcb, out, ssqp, cnt);
}

// Round 8
// 117.954 us; speedup vs baseline: 1.0768x; 1.0768x over previous
//
#include <hip/hip_runtime.h>
#include <hip/hip_bf16.h>

typedef __attribute__((ext_vector_type(8))) short short8;   // 8 x bf16 (4 VGPRs)
typedef __attribute__((ext_vector_type(4))) float f32x4;
using bf16 = __hip_bfloat16;

// Problem sizes: B=32, LQ=LKV=256, HID=1024, EMB=1024, K_fc=2048

__device__ __forceinline__ void glds16(const void* g, void* lds) {
  __builtin_amdgcn_global_load_lds(
      (const __attribute__((address_space(1))) void*)g,
      (__attribute__((address_space(3))) void*)lds, 16, 0, 0);
}

// ---------------- K1: gathers + f32->bf16 conversions (merged) ----------------
__global__ __launch_bounds__(256) void k1_prep(
    const int* __restrict__ captions, const float* __restrict__ Wa,
    const float* __restrict__ H, const float* __restrict__ fcw,
    const int* __restrict__ targets, const float* __restrict__ Wc,
    bf16* __restrict__ EA, bf16* __restrict__ X, bf16* __restrict__ FW,
    bf16* __restrict__ ECT) {
  __shared__ float T[64][67];
  int task = blockIdx.x;
  int tid = threadIdx.x;
  if (task < 17408) {
    const float* src;
    bf16* dst;
    int n;
    if (task < 8192) {
      src = Wa + (size_t)captions[task] * 1024;
      dst = EA + (size_t)task * 1024;
      n = 1024;
    } else if (task < 16384) {
      int t = task - 8192;
      src = H + (size_t)t * 1024;
      dst = X + (size_t)t * 2048;
      n = 1024;
    } else {
      int t = task - 16384;
      src = fcw + (size_t)t * 2048;
      dst = FW + (size_t)t * 2048;
      n = 2048;
    }
    for (int c = tid * 4; c < n; c += 1024) {
      float4 v = *(const float4*)(src + c);
      __hip_bfloat162 p0, p1;
      p0.x = __float2bfloat16(v.x); p0.y = __float2bfloat16(v.y);
      p1.x = __float2bfloat16(v.z); p1.y = __float2bfloat16(v.w);
      *(__hip_bfloat162*)(dst + c) = p0;
      *(__hip_bfloat162*)(dst + c + 2) = p1;
    }
    return;
  }
  int bid = task - 17408;
  int b = bid >> 6;
  int kt = (bid >> 4) & 3;
  int ht = bid & 15;
#pragma unroll
  for (int p = 0; p < 4; ++p) {
    int k = p * 16 + (tid >> 4);
    int idx = targets[b * 256 + kt * 64 + k];
    const float* s = Wc + (size_t)idx * 1024 + ht * 64 + (tid & 15) * 4;
    float4 v = *(const float4*)s;
    int c = (tid & 15) * 4;
    T[k][c] = v.x; T[k][c + 1] = v.y; T[k][c + 2] = v.z; T[k][c + 3] = v.w;
  }
  __syncthreads();
#pragma unroll
  for (int p = 0; p < 8; ++p) {
    int h = p * 8 + (tid >> 5);
    int k = (tid & 31) * 2;
    __hip_bfloat162 o;
    o.x = __float2bfloat16(T[k][h]);
    o.y = __float2bfloat16(T[k + 1][h]);
    *(__hip_bfloat162*)(ECT + ((size_t)b * 1024 + ht * 64 + h) * 256 + kt * 64 + k) = o;
  }
}

// ---------------- K23: fused scores + masked-exp softmax + PV ----------------
__global__ __launch_bounds__(256, 1) void k23_scores_pv(
    bf16* __restrict__ X, const bf16* __restrict__ EA,
    const bf16* __restrict__ ECT, const float* __restrict__ mask) {
  __shared__ __align__(16) char smem[16 * 1024 + 512 + 128 * 1024];
  bf16* p_lds = (bf16*)smem;                    // [32][256] swizzled
  float* red  = (float*)(smem + 16 * 1024);     // [4][32]
  bf16* big   = (bf16*)(smem + 16 * 1024 + 512);// 128KB: scores As+Bs / PV B2

  int p = blockIdx.x;
  int wg = (p & 7) * 32 + (p >> 3);   // chunked XCD swizzle (256 % 8 == 0)
  int b = wg >> 3;
  int mb = wg & 7;
  int tid = threadIdx.x, w = tid >> 6, l = tid & 63;

  const bf16* Ag = X + ((size_t)b * 256 + mb * 32) * 2048;
  const bf16* Bg = EA + (size_t)b * 256 * 1024;
  bf16* As = big;              // 32 x 64
  bf16* Bs = big + 32 * 64;    // 256 x 64

  f32x4 sacc[2][4];
  f32x4 zero = {0.f, 0.f, 0.f, 0.f};
#pragma unroll
  for (int m2 = 0; m2 < 2; ++m2)
#pragma unroll
    for (int n = 0; n < 4; ++n) sacc[m2][n] = zero;

  for (int kt = 0; kt < 16; ++kt) {
    {
      int row = tid >> 3, ss = (tid & 7) ^ (row & 7);
      glds16(Ag + (size_t)row * 2048 + kt * 64 + ss * 8,
             As + (size_t)w * 64 * 8);
    }
#pragma unroll
    for (int i = 0; i < 8; ++i) {
      int c = i * 256 + tid;
      int row = c >> 3, ss = (c & 7) ^ (row & 7);
      glds16(Bg + (size_t)row * 1024 + kt * 64 + ss * 8,
             Bs + (size_t)(i * 256 + w * 64) * 8);
    }
    __syncthreads();
#pragma unroll
    for (int kk = 0; kk < 2; ++kk) {
      short8 a2[2];
#pragma unroll
      for (int m2 = 0; m2 < 2; ++m2) {
        int ar = m2 * 16 + (l & 15);
        int sl = kk * 4 + (l >> 4);
        a2[m2] = *(const short8*)(As + ar * 64 + ((sl ^ (ar & 7)) * 8));
      }
      __builtin_amdgcn_s_setprio(1);
#pragma unroll
      for (int n = 0; n < 4; ++n) {
        int rb = w * 64 + n * 16 + (l & 15);
        int sl = kk * 4 + (l >> 4);
        short8 bfr = *(const short8*)(Bs + rb * 64 + ((sl ^ (rb & 7)) * 8));
#pragma unroll
        for (int m2 = 0; m2 < 2; ++m2)
          sacc[m2][n] = __builtin_amdgcn_mfma_f32_16x16x32_bf16(
              a2[m2], bfr, sacc[m2][n], 0, 0, 0);
      }
      __builtin_amdgcn_s_setprio(0);
    }
    __syncthreads();
  }

  const float* mrow = mask + ((size_t)b * 256 + mb * 32) * 256;
  float s[2][4] = {{0.f, 0.f, 0.f, 0.f}, {0.f, 0.f, 0.f, 0.f}};
#pragma unroll
  for (int m2 = 0; m2 < 2; ++m2)
#pragma unroll
    for (int n = 0; n < 4; ++n)
#pragma unroll
      for (int i = 0; i < 4; ++i) {
        int r = m2 * 16 + ((l >> 4) << 2) + i;
        int c = w * 64 + n * 16 + (l & 15);
        float mv = mrow[r * 256 + c];
        mv = fminf(fmaxf(mv, 0.f), 1.f);
        float ev = expf(sacc[m2][n][i]) * mv;
        sacc[m2][n][i] = ev;
        s[m2][i] += ev;
      }
#pragma unroll
  for (int msk = 1; msk < 16; msk <<= 1)
#pragma unroll
    for (int m2 = 0; m2 < 2; ++m2)
#pragma unroll
      for (int i = 0; i < 4; ++i) s[m2][i] += __shfl_xor(s[m2][i], msk, 64);
  if ((l & 15) == 0) {
#pragma unroll
    for (int m2 = 0; m2 < 2; ++m2)
#pragma unroll
      for (int i = 0; i < 4; ++i)
        red[w * 32 + m2 * 16 + ((l >> 4) << 2) + i] = s[m2][i];
  }
  __syncthreads();
  float inv[2][4];
#pragma unroll
  for (int m2 = 0; m2 < 2; ++m2)
#pragma unroll
    for (int i = 0; i < 4; ++i) {
      int r = m2 * 16 + ((l >> 4) << 2) + i;
      float tot = red[r] + red[32 + r] + red[64 + r] + red[96 + r];
      inv[m2][i] = 1.f / (tot + 1e-10f);
    }
#pragma unroll
  for (int m2 = 0; m2 < 2; ++m2)
#pragma unroll
    for (int n = 0; n < 4; ++n)
#pragma unroll
      for (int i = 0; i < 4; ++i) {
        int r = m2 * 16 + ((l >> 4) << 2) + i;
        int c = w * 64 + n * 16 + (l & 15);
        float pv = sacc[m2][n][i] * inv[m2][i];
        p_lds[r * 256 + (((c >> 3) ^ (r & 7)) << 3) + (c & 7)] =
            __float2bfloat16(pv);
      }
  __syncthreads();

  bf16* XO = X + ((size_t)b * 256 + mb * 32) * 2048 + 1024;
  for (int np = 0; np < 2; ++np) {
    f32x4 acc[2][8];
#pragma unroll
    for (int m2 = 0; m2 < 2; ++m2)
#pragma unroll
      for (int n = 0; n < 8; ++n) acc[m2][n] = zero;

#pragma unroll
    for (int it = 0; it < 16; ++it) {
      int g = it * 64 + l;
      int row = g >> 3, ss = (g & 7) ^ (row & 7);
      glds16(ECT + ((size_t)b * 1024 + np * 512 + w * 128 + row) * 256 + ss * 8,
             big + (size_t)(0 * 4 + w) * 8192 + (size_t)it * 512);
    }
    __syncthreads();
    for (int kt = 0; kt < 4; ++kt) {
      int cur = kt & 1;
      if (kt < 3) {
#pragma unroll
        for (int it = 0; it < 16; ++it) {
          int g = it * 64 + l;
          int row = g >> 3, ss = (g & 7) ^ (row & 7);
          glds16(ECT + ((size_t)b * 1024 + np * 512 + w * 128 + row) * 256 +
                     (kt + 1) * 64 + ss * 8,
                 big + (size_t)((cur ^ 1) * 4 + w) * 8192 + (size_t)it * 512);
        }
      }
      const bf16* Bw = big + (size_t)(cur * 4 + w) * 8192;
#pragma unroll
      for (int kk = 0; kk < 2; ++kk) {
        short8 a2[2];
#pragma unroll
        for (int m2 = 0; m2 < 2; ++m2) {
          int ar = m2 * 16 + (l & 15);
          int sl = kt * 8 + kk * 4 + (l >> 4);
          a2[m2] = *(const short8*)(p_lds + ar * 256 + ((sl ^ (ar & 7)) * 8));
        }
        __builtin_amdgcn_s_setprio(1);
#pragma unroll
        for (int n = 0; n < 8; ++n) {
          int rb = n * 16 + (l & 15);
          int sl = kk * 4 + (l >> 4);
          short8 bfr = *(const short8*)(Bw + rb * 64 + ((sl ^ (rb & 7)) * 8));
#pragma unroll
          for (int m2 = 0; m2 < 2; ++m2)
            acc[m2][n] = __builtin_amdgcn_mfma_f32_16x16x32_bf16(
                a2[m2], bfr, acc[m2][n], 0, 0, 0);
        }
        __builtin_amdgcn_s_setprio(0);
      }
      __syncthreads();
    }
#pragma unroll
    for (int m2 = 0; m2 < 2; ++m2)
#pragma unroll
      for (int n = 0; n < 8; ++n) {
        int rl = m2 * 16 + ((l >> 4) << 2);
        int col = np * 512 + w * 128 + n * 16 + (l & 15);
#pragma unroll
        for (int i = 0; i < 4; ++i)
          XO[(size_t)(rl + i) * 2048 + col] = __float2bfloat16(acc[m2][n][i]);
      }
  }
}

// ---------------- K4: out = X @ FW^T + fc_b + 1e-10 (f32) ----------------
// Proven sync-only 2-phase dbuf (R5/R6). At the m233 2-phase plateau.
#define K4A (256 * 64)
#define K4B (128 * 64)

__device__ __forceinline__ void k4_stage(const bf16* __restrict__ Ag,
                                         const bf16* __restrict__ Bg, int kt,
                                         bf16* As, bf16* Bs, int tid, int w) {
#pragma unroll
  for (int i = 0; i < 4; ++i) {
    int c = i * 512 + tid;
    int row = c >> 3, ss = (c & 7) ^ (row & 7);
    glds16(Ag + (size_t)row * 2048 + kt * 64 + ss * 8,
           As + (size_t)(i * 512 + w * 64) * 8);
  }
#pragma unroll
  for (int i = 0; i < 2; ++i) {
    int c = i * 512 + tid;
    int row = c >> 3, ss = (c & 7) ^ (row & 7);
    glds16(Bg + (size_t)row * 2048 + kt * 64 + ss * 8,
           Bs + (size_t)(i * 512 + w * 64) * 8);
  }
}

__device__ __forceinline__ void k4_tile(const bf16* As, const bf16* Bs,
                                        int wr, int wc, int l,
                                        f32x4 (&acc)[4][4]) {
  short8 a[2][4], b[2][4];
#pragma unroll
  for (int kk = 0; kk < 2; ++kk)
#pragma unroll
    for (int n = 0; n < 4; ++n) {
      int row = wc * 64 + n * 16 + (l & 15);
      int slot = kk * 4 + (l >> 4);
      b[kk][n] = *(const short8*)(Bs + row * 64 + ((slot ^ (row & 7)) * 8));
    }
#pragma unroll
  for (int kk = 0; kk < 2; ++kk)
#pragma unroll
    for (int m = 0; m < 4; ++m) {
      int row = wr * 64 + m * 16 + (l & 15);
      int slot = kk * 4 + (l >> 4);
      a[kk][m] = *(const short8*)(As + row * 64 + ((slot ^ (row & 7)) * 8));
    }
  __builtin_amdgcn_s_setprio(1);
#pragma unroll
  for (int kk = 0; kk < 2; ++kk)
#pragma unroll
    for (int m = 0; m < 4; ++m)
#pragma unroll
      for (int n = 0; n < 4; ++n)
        acc[m][n] = __builtin_amdgcn_mfma_f32_16x16x32_bf16(
            a[kk][m], b[kk][n], acc[m][n], 0, 0, 0);
  __builtin_amdgcn_s_setprio(0);
}

__global__ __launch_bounds__(512, 1) void k4_fc(
    const bf16* __restrict__ X, const bf16* __restrict__ FW,
    const float* __restrict__ fcb, float* __restrict__ out) {
  __shared__ __align__(16) bf16 As[2][K4A];   // 64 KB
  __shared__ __align__(16) bf16 Bs[2][K4B];   // 32 KB
  int p = blockIdx.x;
  int wg = (p & 7) * 32 + (p >> 3);   // chunked XCD swizzle (256 % 8 == 0)
  int mb = wg >> 3;
  int nb = wg & 7;
  int tid = threadIdx.x, w = tid >> 6, l = tid & 63;
  int wr = w >> 1, wc = w & 1;
  f32x4 acc[4][4];
  f32x4 zero = {0.f, 0.f, 0.f, 0.f};
#pragma unroll
  for (int m = 0; m < 4; ++m)
#pragma unroll
    for (int n = 0; n < 4; ++n) acc[m][n] = zero;

  const bf16* Ag = X + (size_t)mb * 256 * 2048;
  const bf16* Bg = FW + (size_t)nb * 128 * 2048;

  k4_stage(Ag, Bg, 0, As[0], Bs[0], tid, w);
  __syncthreads();
  for (int t = 0; t < 32; ++t) {
    int cur = t & 1;
    if (t < 31)
      k4_stage(Ag, Bg, t + 1, As[cur ^ 1], Bs[cur ^ 1], tid, w);
    k4_tile(As[cur], Bs[cur], wr, wc, l, acc);
    __syncthreads();
  }

  float bias[4];
#pragma unroll
  for (int n = 0; n < 4; ++n)
    bias[n] = fcb[nb * 128 + wc * 64 + n * 16 + (l & 15)];
#pragma unroll
  for (int m = 0; m < 4; ++m) {
    int rbase = mb * 256 + wr * 64 + m * 16 + ((l >> 4) << 2);
#pragma unroll
    for (int n = 0; n < 4; ++n) {
      int col = nb * 128 + wc * 64 + n * 16 + (l & 15);
#pragma unroll
      for (int i = 0; i < 4; ++i)
        out[(size_t)(rbase + i) * 1024 + col] = acc[m][n][i] + bias[n] + 1e-10f;
    }
  }
}

// ---------------- K5: in-place row L2 normalize ----------------
__global__ __launch_bounds__(256) void k5_norm(float* __restrict__ y) {
  __shared__ float red[4];
  int row = blockIdx.x;
  float* p = y + (size_t)row * 1024;
  int tid = threadIdx.x;
  float4 v = *(const float4*)(p + tid * 4);
  float ss = v.x * v.x + v.y * v.y + v.z * v.z + v.w * v.w;
#pragma unroll
  for (int m = 1; m < 64; m <<= 1) ss += __shfl_xor(ss, m, 64);
  if ((tid & 63) == 0) red[tid >> 6] = ss;
  __syncthreads();
  float tot = red[0] + red[1] + red[2] + red[3];
  float inv = 1.f / (sqrtf(tot) + 1e-8f);
  float4 o;
  o.x = v.x * inv; o.y = v.y * inv; o.z = v.z * inv; o.w = v.w * inv;
  *(float4*)(p + tid * 4) = o;
}

extern "C" void kernel_launch(void* const* d_in, const int* in_sizes, int n_in,
                              void* d_out, int out_size, void* d_ws, size_t ws_size,
                              hipStream_t stream) {
  const int* captions = (const int*)d_in[0];
  const float* H = (const float*)d_in[1];
  const int* targets = (const int*)d_in[2];
  const float* mask = (const float*)d_in[3];
  const float* Wa = (const float*)d_in[4];
  const float* Wc = (const float*)d_in[5];
  const float* fcw = (const float*)d_in[6];
  const float* fcb = (const float*)d_in[7];
  float* out = (float*)d_out;

  char* ws = (char*)d_ws;
  bf16* EA = (bf16*)(ws);                        // 16 MB [32][256][1024]
  bf16* ECT = (bf16*)(ws + (16u << 20));         // 16 MB [32][1024][256]
  bf16* X = (bf16*)(ws + (36u << 20));           // 32 MB [8192][2048]
  bf16* FW = (bf16*)(ws + (68u << 20));          //  4 MB [1024][2048]

  k1_prep<<<19456, 256, 0, stream>>>(captions, Wa, H, fcw, targets, Wc,
                                     EA, X, FW, ECT);
  k23_scores_pv<<<256, 256, 0, stream>>>(X, EA, ECT, mask);
  k4_fc<<<256, 512, 0, stream>>>(X, FW, fcb, out);
  k5_norm<<<8192, 256, 0, stream>>>(out);
}